// Round 1
// 324.802 us; speedup vs baseline: 1.0352x; 1.0352x over previous
//
#include <hip/hip_runtime.h>
#include <math.h>

#define KK 8
#define H 250          // SIZE == h1
#define MDIM 576
#define NB 2048
#define HA 100
#define ROWS (NB*KK)   // 16384
#define PROWS (ROWS*7) // 114688 pair rows
#define PQS 512        // PQb row stride (ushort): P at 0..249, Q at 256..505
#define KP 1088        // padded K for out GEMM (1076 -> 34*32)
#define CSLD 352       // Cs row stride (ushort): 250 ctx + 100 att + 2 pad
#define EPS 1e-5f

typedef unsigned short ushort_t;
typedef short short8 __attribute__((ext_vector_type(8)));
typedef unsigned short us8 __attribute__((ext_vector_type(8)));
typedef unsigned short us4 __attribute__((ext_vector_type(4)));
typedef unsigned short us2 __attribute__((ext_vector_type(2)));
typedef float f32x4 __attribute__((ext_vector_type(4)));

// ---- DPP tree reduction: 6 VALU dpp-adds + 1 readlane, zero DS-pipe ops ----
// old=0 + bound_ctrl=1 so GCNDPPCombine can fold the mov_dpp into v_add_f32_dpp.
template<int CTRL>
__device__ __forceinline__ float dpp_add_f32(float x) {
    const int s = __builtin_amdgcn_update_dpp(
        0, __builtin_bit_cast(int, x), CTRL, 0xF, 0xF, true);
    return x + __builtin_bit_cast(float, s);
}
// full-wave (64-lane) sum; result broadcast wave-uniform via readlane(63)
__device__ __forceinline__ float wave_sum_dpp(float x) {
    x = dpp_add_f32<0x111>(x);  // row_shr:1
    x = dpp_add_f32<0x112>(x);  // row_shr:2
    x = dpp_add_f32<0x114>(x);  // row_shr:4
    x = dpp_add_f32<0x118>(x);  // row_shr:8
    x = dpp_add_f32<0x142>(x);  // row_bcast:15
    x = dpp_add_f32<0x143>(x);  // row_bcast:31 -> lane 63 holds total
    return __builtin_bit_cast(float, __builtin_amdgcn_readlane(
        __builtin_bit_cast(int, x), 63));
}

__device__ __forceinline__ void async_copy16(const void* g, void* l) {
    __builtin_amdgcn_global_load_lds(
        (const __attribute__((address_space(1))) void*)g,
        (__attribute__((address_space(3))) void*)l, 16, 0, 0);
}

__device__ __forceinline__ ushort_t f2bf(float v) {
    union { float f; unsigned int u; } c; c.f = v;
    unsigned int x = c.u;
    x += 0x7fff + ((x >> 16) & 1);   // RNE
    return (ushort_t)(x >> 16);
}
__device__ __forceinline__ float bf2f(ushort_t v) {
    union { unsigned int u; float f; } c; c.u = ((unsigned int)v) << 16;
    return c.f;
}
// fast tanh: 1 - 2/(exp(2x)+1)  (v_exp + v_rcp; ~1e-6 rel err, << bf16 ulp)
__device__ __forceinline__ float ftanh(float x) {
    const float e = __expf(2.f * x);
    return 1.f - 2.f * __builtin_amdgcn_rcpf(e + 1.f);
}
__device__ __forceinline__ float fsigmoid(float x) {
    return __builtin_amdgcn_rcpf(1.f + __expf(-x));
}

// ---- fused prep: Wt | Wpq | Wca | Wenc | Sb | x->Abuf ----
__global__ __launch_bounds__(256) void k_prep(
    const float* __restrict__ out_W, const float* __restrict__ core_W,
    const float* __restrict__ ctx_W, const float* __restrict__ att_W1,
    const float* __restrict__ enc_W, const float* __restrict__ state,
    const float* __restrict__ x,
    ushort_t* __restrict__ Wt, ushort_t* __restrict__ Wpq,
    ushort_t* __restrict__ Wca, ushort_t* __restrict__ Wenc,
    ushort_t* __restrict__ Sb, ushort_t* __restrict__ Abuf)
{
    const int b = blockIdx.x, t = threadIdx.x;
    if (b < 256) {                      // Wt[n][k] = out_W[k][n]
        const int n = b;
        for (int k = t; k < KP; k += 256) {
            const float v = (n < H && k < 1076) ? out_W[(size_t)k * H + n] : 0.f;
            Wt[(size_t)n * KP + k] = f2bf(v);
        }
    } else if (b < 768) {               // Wpq
        const int n = b - 256, k = t;
        float v = 0.f;
        if (k < H) {
            if (n < H)                    v = core_W[(size_t)k * H + n];
            else if (n >= 256 && n < 506) v = core_W[(size_t)(H + k) * H + (n - 256)];
        }
        Wpq[(size_t)n * 256 + k] = f2bf(v);
    } else if (b < 1152) {              // Wca
        const int n = b - 768, k = t;
        float v = 0.f;
        if (k < H) {
            if (n < H)           v = ctx_W[(size_t)k * H + n];
            else if (n < H + HA) v = att_W1[(size_t)k * HA + (n - H)];
        }
        Wca[(size_t)n * 256 + k] = f2bf(v);
    } else if (b < 1408) {              // Wenc[n][k] = enc_W[k][n]
        const int n = b - 1152, k = t;
        const float v = (n < H && k < H) ? enc_W[(size_t)k * H + n] : 0.f;
        Wenc[(size_t)n * 256 + k] = f2bf(v);
    } else if (b < 2432) {              // Sb: state padded to 256, bf16
        const int r0 = (b - 1408) * 16;
        for (int idx = t; idx < 16 * 256; idx += 256) {
            const int r = r0 + (idx >> 8), k = idx & 255;
            const float v = (k < H) ? state[(size_t)r * H + k] : 0.f;
            Sb[(size_t)r * 256 + k] = f2bf(v);
        }
    } else {                            // Abuf cols [500,1088): x + pad
        const int row = b - 2432;
        for (int c = 500 + t; c < KP; c += 256) {
            const float v = (c < 500 + MDIM) ? x[(size_t)row * MDIM + (c - 500)] : 0.f;
            Abuf[(size_t)row * KP + c] = f2bf(v);
        }
    }
}

// N-resident bf16 MFMA GEMM (k_cs-style): C[m][n] = sum_k A[m][k]*B[n][k] (+bias)
// Whole N = NT*64 resident in LDS per block -> A fetched exactly once.
// 512 thr = 8 waves (2m x 4n); per wave 32 rows x NT*16 cols; acc[2][NT].
template<int NT>
__global__ __launch_bounds__(512, NT == 8 ? 2 : 4) void k_gemm_nres(
    const ushort_t* __restrict__ A, int lda,
    const ushort_t* __restrict__ B, int ldb,
    void* __restrict__ Cp, int ldc,
    const float* __restrict__ bias,
    int ksteps, int nlim, int bf16out)
{
    constexpr int NROWS = NT * 64;                    // B rows resident
    __shared__ __align__(16) ushort_t As[64 * 32];    // 4 KB
    __shared__ __align__(16) ushort_t Bs[NROWS * 32]; // NT*4 KB
    const int tid = threadIdx.x, lane = tid & 63, wave = tid >> 6;
    const int wm = wave >> 2, wn = wave & 3;
    const int R0 = (int)blockIdx.x * 64;

    const int ar = tid >> 2, acb = tid & 3;
    const bool aon = tid < 256;
    const int acl = acb ^ ((ar >> 1) & 3);
    const ushort_t* gA = A + (size_t)(R0 + ar) * lda + acl * 8;

    const int q = lane >> 4, fr = lane & 15;

    f32x4 acc[2][NT] = {};
    for (int ks = 0; ks < ksteps; ++ks) {
        const int k0 = ks * 32;
        if (aon) async_copy16(gA + k0, &As[tid * 8]);
#pragma unroll
        for (int it = 0; it < NT / 2; ++it) {
            const int ci  = it * 512 + tid;
            const int rb  = ci >> 2, cb2 = ci & 3;
            const int clb = cb2 ^ ((rb >> 1) & 3);
            async_copy16(B + (size_t)rb * ldb + k0 + clb * 8, &Bs[ci * 8]);
        }
        __syncthreads();
        short8 a[2];
#pragma unroll
        for (int ms = 0; ms < 2; ++ms) {
            const int row = wm * 32 + ms * 16 + fr;
            a[ms] = *(const short8*)&As[(row * 4 + (q ^ ((row >> 1) & 3))) * 8];
        }
#pragma unroll
        for (int nt = 0; nt < NT; ++nt) {
            const int n = wn * (NT * 16) + nt * 16 + fr;
            const short8 b = *(const short8*)&Bs[(n * 4 + (q ^ ((n >> 1) & 3))) * 8];
#pragma unroll
            for (int ms = 0; ms < 2; ++ms)
                acc[ms][nt] = __builtin_amdgcn_mfma_f32_16x16x32_bf16(
                    a[ms], b, acc[ms][nt], 0, 0, 0);
        }
        __syncthreads();
    }

#pragma unroll
    for (int ms = 0; ms < 2; ++ms)
#pragma unroll
        for (int nt = 0; nt < NT; ++nt) {
            const int col = wn * (NT * 16) + nt * 16 + fr;
            if (col >= nlim) continue;
            const float bv = bias ? bias[col] : 0.f;
#pragma unroll
            for (int reg = 0; reg < 4; ++reg) {
                const int row = R0 + wm * 32 + ms * 16 + q * 4 + reg;
                const float v = acc[ms][nt][reg] + bv;
                if (bf16out) ((ushort_t*)Cp)[(size_t)row * ldc + col] = f2bf(v);
                else         ((float*)Cp)[(size_t)row * ldc + col] = v;
            }
        }
}

// LN(relu(Epre + enc_b)) -> Abuf cols [0,250). One wave per row, us4 loads.
__global__ __launch_bounds__(256) void k_lnenc(const ushort_t* __restrict__ Epre,
    const float* __restrict__ eb, const float* __restrict__ eg,
    const float* __restrict__ ebt, ushort_t* __restrict__ Abuf)
{
    const int wave = threadIdx.x >> 6, lane = threadIdx.x & 63;
    const int row = blockIdx.x * 4 + wave;
    const int c0 = 4 * lane;

    const us4 v = *(const us4*)&Epre[(size_t)row * 256 + c0];
    float y[4]; float sm = 0.f, sq = 0.f;
#pragma unroll
    for (int t = 0; t < 4; ++t) {
        const int cc = c0 + t;
        float z = 0.f;
        if (cc < H) z = fmaxf(bf2f(v[t]) + eb[cc], 0.f);
        y[t] = z; sm += z; sq += z * z;
    }
    sm = wave_sum_dpp(sm);
    sq = wave_sum_dpp(sq);
    const float mu = sm * (1.f / H);
    const float rs = __builtin_amdgcn_rsqf(sq * (1.f / H) - mu * mu + EPS);
    ushort_t o[4];
#pragma unroll
    for (int t = 0; t < 4; ++t) {
        const int cc = c0 + t;
        o[t] = (cc < H) ? f2bf((y[t] - mu) * rs * eg[cc] + ebt[cc]) : (ushort_t)0;
    }
    ushort_t* dst = Abuf + (size_t)row * KP + c0;
    if (c0 + 3 < H) { *(us4*)dst = (us4){o[0], o[1], o[2], o[3]}; }
    else {
        if (c0 + 1 < H) *(us2*)dst = (us2){o[0], o[1]};
    }
}

// Co[r][0:256] = LN(relu(P_g + Q_qr + core_b)) bf16. One wave per GROUP.
// All 7 partner Q rows prefetched; per-row sums reduced via DPP trees.
__global__ __launch_bounds__(256) void k_core(const ushort_t* __restrict__ PQb,
    const float* __restrict__ core_b, const float* __restrict__ core_g,
    const float* __restrict__ core_bt, ushort_t* __restrict__ Co)
{
    const int wave = threadIdx.x >> 6, lane = threadIdx.x & 63;
    const int g = blockIdx.x * 4 + wave;        // group 0..16383
    const int i = g & 7;
    const int c = lane * 4;

    const us4 pu = *(const us4*)&PQb[(size_t)g * PQS + c];
    us4 qu[7];
#pragma unroll
    for (int jj = 0; jj < 7; ++jj) {
        const int j = jj + (jj >= i ? 1 : 0);
        const int qr = (g & ~7) + j;
        qu[jj] = *(const us4*)&PQb[(size_t)qr * PQS + 256 + c];
    }
    float pe[4], cb[4], cg[4], cbt[4]; bool vl[4];
#pragma unroll
    for (int t = 0; t < 4; ++t) {
        vl[t]  = (c + t) < H;
        pe[t]  = bf2f(pu[t]);
        cb[t]  = vl[t] ? core_b[c + t]  : 0.f;
        cg[t]  = vl[t] ? core_g[c + t]  : 0.f;
        cbt[t] = vl[t] ? core_bt[c + t] : 0.f;
    }
    float z[7][4], red[7][2];
#pragma unroll
    for (int jj = 0; jj < 7; ++jj) {
        float sm = 0.f, sq = 0.f;
#pragma unroll
        for (int t = 0; t < 4; ++t) {
            const float zz = vl[t] ? fmaxf(pe[t] + bf2f(qu[jj][t]) + cb[t], 0.f) : 0.f;
            z[jj][t] = zz; sm += zz; sq = fmaf(zz, zz, sq);
        }
        red[jj][0] = sm; red[jj][1] = sq;
    }
    // 14 independent DPP reduction chains (VALU only, no DS pipe)
#pragma unroll
    for (int jj = 0; jj < 7; ++jj) {
        red[jj][0] = wave_sum_dpp(red[jj][0]);
        red[jj][1] = wave_sum_dpp(red[jj][1]);
    }
#pragma unroll
    for (int jj = 0; jj < 7; ++jj) {
        const float mu = red[jj][0] * (1.f / H);
        const float rs = __builtin_amdgcn_rsqf(red[jj][1] * (1.f / H) - mu * mu + EPS);
        us4 o;
#pragma unroll
        for (int t = 0; t < 4; ++t)
            o[t] = vl[t] ? f2bf((z[jj][t] - mu) * rs * cg[t] + cbt[t]) : (ushort_t)0;
        *(us4*)&Co[((size_t)g * 7 + jj) * 256 + c] = o;
    }
}

// Cs[r][0:352] = Co_r @ [ctxW|attW1]^T (bf16 out). Pure async-staged GEMM:
// M=64/block, N=384 resident. 512 thr = 8 waves (2x4); acc[2][6] = 48 AGPR/wave.
__global__ __launch_bounds__(512, 4) void k_cs(
    const ushort_t* __restrict__ Co,
    const ushort_t* __restrict__ Wca,   // [384][256] bf16
    ushort_t* __restrict__ Cs)
{
    __shared__ __align__(16) ushort_t As[64 * 32];    // 4096 B
    __shared__ __align__(16) ushort_t Bs[384 * 32];   // 24576 B
    const int tid = threadIdx.x, lane = tid & 63, wave = tid >> 6;
    const int wm = wave >> 2, wn = wave & 3;
    const int R0 = (int)blockIdx.x * 64;

    const int ar = tid >> 2, acb = tid & 3;
    const bool aon = tid < 256;
    const int acl = acb ^ ((ar >> 1) & 3);
    const ushort_t* gA = Co + (size_t)(R0 + ar) * 256 + acl * 8;

    const int q = lane >> 4, fr = lane & 15;

    f32x4 acc[2][6] = {};
    for (int ks = 0; ks < 8; ++ks) {
        const int k0 = ks * 32;
        if (aon) async_copy16(gA + k0, &As[tid * 8]);
#pragma unroll
        for (int it = 0; it < 3; ++it) {
            const int ci  = it * 512 + tid;
            const int rb  = ci >> 2, cb2 = ci & 3;
            const int clb = cb2 ^ ((rb >> 1) & 3);
            async_copy16(Wca + (size_t)rb * 256 + k0 + clb * 8, &Bs[ci * 8]);
        }
        __syncthreads();
        short8 a[2];
#pragma unroll
        for (int ms = 0; ms < 2; ++ms) {
            const int row = wm * 32 + ms * 16 + fr;
            a[ms] = *(const short8*)&As[(row * 4 + (q ^ ((row >> 1) & 3))) * 8];
        }
#pragma unroll
        for (int nt = 0; nt < 6; ++nt) {
            const int n = wn * 96 + nt * 16 + fr;
            const short8 b = *(const short8*)&Bs[(n * 4 + (q ^ ((n >> 1) & 3))) * 8];
#pragma unroll
            for (int ms = 0; ms < 2; ++ms)
                acc[ms][nt] = __builtin_amdgcn_mfma_f32_16x16x32_bf16(
                    a[ms], b, acc[ms][nt], 0, 0, 0);
        }
        __syncthreads();
    }

#pragma unroll
    for (int ms = 0; ms < 2; ++ms)
#pragma unroll
        for (int nt = 0; nt < 6; ++nt) {
            const int col = wn * 96 + nt * 16 + fr;
            if (col >= CSLD) continue;
#pragma unroll
            for (int reg = 0; reg < 4; ++reg) {
                const int row = R0 + wm * 32 + ms * 16 + q * 4 + reg;
                Cs[(size_t)row * CSLD + col] = f2bf(acc[ms][nt][reg]);
            }
        }
}

// eff[g] = sum_j sigmoid(att(row)) * LN_ctx(row). One wave per group.
// All 7 rows prefetched; 35 independent DPP reduction chains (no DS pipe).
// NOTE: att columns 250..255 fall in the e<4 lane range (lane 62/63) — the
// e<4 path MUST dispatch on eC/eA per element (round-10 bug: ctx-only).
__global__ __launch_bounds__(256) void k_eff(const ushort_t* __restrict__ Cs,
    const float* __restrict__ ctx_b, const float* __restrict__ ctx_g, const float* __restrict__ ctx_bt,
    const float* __restrict__ att_b1, const float* __restrict__ att_g, const float* __restrict__ att_bt,
    const float* __restrict__ attW2, const float* __restrict__ att_b2,
    ushort_t* __restrict__ Abuf)
{
    const int wave = threadIdx.x >> 6, lane = threadIdx.x & 63;
    const int g = blockIdx.x * 4 + wave;
    const int c0 = 4 * lane;           // 0..252
    const int c1 = 256 + 2 * lane;     // 256..382, valid while lane<48
    const bool l48 = lane < 48;

    int ce[6]; bool eC[6], eA[6]; float b_[6], g_[6], bt_[6], w2_[6], gw[6];
#pragma unroll
    for (int e = 0; e < 6; ++e) {
        ce[e] = (e < 4) ? (c0 + e) : (c1 + (e - 4));
        const bool vld = (e < 4) || l48;
        eC[e] = vld && (ce[e] < H);
        eA[e] = vld && (ce[e] >= H) && (ce[e] < H + HA);
        if (eC[e])      { b_[e] = ctx_b[ce[e]]; g_[e] = ctx_g[ce[e]]; bt_[e] = ctx_bt[ce[e]]; w2_[e] = 0.f; }
        else if (eA[e]) { const int ca = ce[e] - H;
                          b_[e] = att_b1[ca]; g_[e] = att_g[ca]; bt_[e] = att_bt[ca]; w2_[e] = attW2[ca]; }
        else            { b_[e] = g_[e] = bt_[e] = w2_[e] = 0.f; }
        gw[e] = eA[e] ? g_[e] * w2_[e] : 0.f;
    }
    // row-invariant attention sums
    float sgw = 0.f, sbw = 0.f;
#pragma unroll
    for (int e = 0; e < 6; ++e) if (eA[e]) {
        sgw += g_[e] * w2_[e];
        sbw += bt_[e] * w2_[e];
    }
    sgw = wave_sum_dpp(sgw);
    sbw = wave_sum_dpp(sbw);
    const float ab2 = att_b2[0] + sbw;

    // Phase A: prefetch all 7 rows
    us4 v0[7]; us2 v1[7];
#pragma unroll
    for (int jj = 0; jj < 7; ++jj) {
        const size_t base = ((size_t)g * 7 + jj) * CSLD;
        v0[jj] = *(const us4*)&Cs[base + c0];
        v1[jj] = l48 ? *(const us2*)&Cs[base + c1] : (us2){0, 0};
    }

    // Phase B: elementwise partial sums per row (eC/eA dispatch on ALL 6 slots)
    float z[7][4], red[7][5];
#pragma unroll
    for (int jj = 0; jj < 7; ++jj) {
        float smc = 0.f, sqc = 0.f, sma = 0.f, sqa = 0.f, szgw = 0.f;
#pragma unroll
        for (int e = 0; e < 6; ++e) {
            const float raw = (e < 4) ? bf2f(v0[jj][e]) : bf2f(v1[jj][e - 4]);
            float zz = 0.f;
            if (eC[e]) {
                zz = fmaxf(raw + b_[e], 0.f);
                smc += zz; sqc = fmaf(zz, zz, sqc);
            } else if (eA[e]) {
                const float za = ftanh(raw + b_[e]);
                sma += za; sqa = fmaf(za, za, sqa);
                szgw = fmaf(za, gw[e], szgw);
            }
            if (e < 4) z[jj][e] = zz;
        }
        red[jj][0] = smc; red[jj][1] = sqc; red[jj][2] = sma;
        red[jj][3] = sqa; red[jj][4] = szgw;
    }

    // Phase C: 35 independent DPP tree reductions (VALU-only)
#pragma unroll
    for (int jj = 0; jj < 7; ++jj)
#pragma unroll
        for (int v = 0; v < 5; ++v)
            red[jj][v] = wave_sum_dpp(red[jj][v]);

    // Phase D: per-row scalars + accumulation
    float A4[4] = {0.f, 0.f, 0.f, 0.f};
    float S0 = 0.f, S1 = 0.f;
#pragma unroll
    for (int jj = 0; jj < 7; ++jj) {
        const float muC = red[jj][0] * (1.f / H);
        const float rsC = __builtin_amdgcn_rsqf(red[jj][1] * (1.f / H) - muC * muC + EPS);
        const float muA = red[jj][2] * (1.f / HA);
        const float rsA = __builtin_amdgcn_rsqf(red[jj][3] * (1.f / HA) - muA * muA + EPS);
        const float dot = rsA * (red[jj][4] - muA * sgw) + ab2;
        const float ag  = fsigmoid(dot);
        const float cj  = ag * rsC;
        S0 += ag; S1 = fmaf(cj, muC, S1);
#pragma unroll
        for (int e = 0; e < 4; ++e) A4[e] = fmaf(cj, z[jj][e], A4[e]);
    }
    ushort_t o[4];
#pragma unroll
    for (int e = 0; e < 4; ++e)
        o[e] = f2bf(g_[e] * (A4[e] - S1) + bt_[e] * S0);
    ushort_t* dst = Abuf + (size_t)g * KP + H + c0;
    if (c0 + 1 < H) *(us2*)dst       = (us2){o[0], o[1]};
    if (c0 + 3 < H) *(us2*)(dst + 2) = (us2){o[2], o[3]};
}

extern "C" void kernel_launch(void* const* d_in, const int* in_sizes, int n_in,
                              void* d_out, int out_size, void* d_ws, size_t ws_size,
                              hipStream_t stream)
{
    const float* x      = (const float*)d_in[0];
    const float* state  = (const float*)d_in[1];
    const float* enc_W  = (const float*)d_in[2];
    const float* enc_b  = (const float*)d_in[3];
    const float* enc_g  = (const float*)d_in[4];
    const float* enc_bt = (const float*)d_in[5];
    const float* core_W = (const float*)d_in[6];
    const float* core_b = (const float*)d_in[7];
    const float* core_g = (const float*)d_in[8];
    const float* core_bt= (const float*)d_in[9];
    const float* ctx_W  = (const float*)d_in[10];
    const float* ctx_b  = (const float*)d_in[11];
    const float* ctx_g  = (const float*)d_in[12];
    const float* ctx_bt = (const float*)d_in[13];
    const float* att_W1 = (const float*)d_in[14];
    const float* att_b1 = (const float*)d_in[15];
    const float* att_g  = (const float*)d_in[16];
    const float* att_bt = (const float*)d_in[17];
    const float* att_W2 = (const float*)d_in[18];
    const float* att_b2 = (const float*)d_in[19];
    const float* out_W  = (const float*)d_in[20];
    const float* out_b  = (const float*)d_in[21];
    float* out = (float*)d_out;

    // layout (ushort units); Sb/Epre/PQb alias the Cs region (dead before k_cs)
    ushort_t* Abuf = (ushort_t*)d_ws;                   // 16384*1088      (35.7 MB)
    ushort_t* Wt   = Abuf + (size_t)ROWS * KP;          // 256*1088
    ushort_t* Wpq  = Wt + (size_t)256 * KP;             // 512*256
    ushort_t* Wca  = Wpq + (size_t)512 * 256;           // 384*256
    ushort_t* Wenc = Wca + (size_t)384 * 256;           // 256*256
    ushort_t* Co   = Wenc + (size_t)256 * 256;          // 114688*256     (58.7 MB)
    ushort_t* Cs   = Co + (size_t)PROWS * 256;          // 114688*352     (80.7 MB)
    ushort_t* Sb   = Cs;                                // 16384*256  (aliased)
    ushort_t* Epre = Sb + (size_t)ROWS * 256;           // 16384*256  (aliased)
    ushort_t* PQb  = Epre + (size_t)ROWS * 256;         // 16384*512  (aliased)

    k_prep  <<<2432 + ROWS, 256, 0, stream>>>(out_W, core_W, ctx_W, att_W1, enc_W,
                                              state, x, Wt, Wpq, Wca, Wenc, Sb, Abuf);
    // Epre = state @ enc_W  (bf16 MFMA, N=256 resident)
    k_gemm_nres<4><<<ROWS / 64, 512, 0, stream>>>(Sb, 256, Wenc, 256, Epre, 256,
                                                  nullptr, 8, 256, 1);
    k_lnenc <<<ROWS / 4, 256, 0, stream>>>(Epre, enc_b, enc_g, enc_bt, Abuf);
    // PQb = s1 @ [W_top | W_bot]  (bf16 MFMA, N=512 resident, bf16 out)
    k_gemm_nres<8><<<ROWS / 64, 512, 0, stream>>>(Abuf, KP, Wpq, 256, PQb, PQS,
                                                  nullptr, 8, 512, 1);
    k_core  <<<ROWS / 4, 256, 0, stream>>>(PQb, core_b, core_g, core_bt, Co);
    k_cs    <<<PROWS / 64, 512, 0, stream>>>(Co, Wca, Cs);
    k_eff   <<<ROWS / 4, 256, 0, stream>>>(Cs, ctx_b, ctx_g, ctx_bt,
                                           att_b1, att_g, att_bt, att_W2, att_b2,
                                           Abuf);
    // out = [s1 | eff | x] @ out_W + b  (bf16 MFMA, N=256 resident, fp32 out)
    k_gemm_nres<4><<<ROWS / 64, 512, 0, stream>>>(Abuf, KP, Wt, KP, out, H,
                                                  out_b, KP / 32, 250, 0);
}